// Round 8
// baseline (232.522 us; speedup 1.0000x reference)
//
#include <hip/hip_runtime.h>
#include <hip/hip_bf16.h>
#include <stdint.h>
#include <math.h>

#define BB 32768
#define FEAT 512
#define SPD_H 128
#define CTRL_H 256
#define NCMD 4

typedef __attribute__((ext_vector_type(8))) short bf16x8;
typedef __attribute__((ext_vector_type(4))) float f32x4;

__device__ __forceinline__ unsigned short f2bf(float f) {
  union { float f; uint32_t u; } v; v.f = f;
  uint32_t u = v.u;
  return (unsigned short)((u + 0x7fffu + ((u >> 16) & 1u)) >> 16); // RNE
}

// async global->LDS, 16B per lane; LDS dest = wave-uniform base + lane*16
__device__ __forceinline__ void async16(const unsigned short* g, unsigned short* l) {
  __builtin_amdgcn_global_load_lds(
      (const __attribute__((address_space(1))) unsigned int*)g,
      (__attribute__((address_space(3))) unsigned int*)l, 16, 0, 0);
}

// ------- 128x128 bf16 MFMA GEMM tile, depth-2 counted-vmcnt pipeline ---------
// T3/T4: 3 LDS buffers; chunk k+2 issued while chunk k computes; s_waitcnt
// vmcnt(8) (= chunk k landed, k+1/k+2 stay in flight) + raw s_barrier pair.
// vmcnt FIFO completion makes the counts safe even if the compiler hoists
// loop-invariant loads. T5 setprio around the MFMA cluster.
// 48 KB dynamic LDS (3 x (As 8K + Bs 8K)); epilogue bounce reuses it.
__device__ __forceinline__ void gemm128_db(
    const unsigned short* __restrict__ A, int lda,
    const int* __restrict__ perm, int m_start, int m_cnt,
    const unsigned short* __restrict__ W, const float* __restrict__ bi,
    unsigned short* __restrict__ C, int ldc, int relu, int K, int mt, int nt) {
  extern __shared__ __align__(16) unsigned char dynsm[];
  unsigned short* As = (unsigned short*)dynsm;     // 3 bufs x [128][32]
  unsigned short* Bs = As + 3 * 4096;              // 3 bufs x [128][32]

  const int m0 = mt * 128;
  if (m0 >= m_cnt) return;
  const int n0 = nt * 128;
  const int t = threadIdx.x;
  const int w = t >> 6, lane = t & 63;
  const int wm = w & 1, wn = w >> 1;

  f32x4 acc[4][4];
#pragma unroll
  for (int i = 0; i < 4; ++i)
#pragma unroll
    for (int j = 0; j < 4; ++j)
#pragma unroll
      for (int r = 0; r < 4; ++r) acc[i][j][r] = 0.f;

  const int fr = lane & 15;
  const int fk = (lane >> 4) * 8;

  const unsigned short* agp[2]; const unsigned short* bgp[2];
  unsigned short* al[2]; unsigned short* bl[2];
#pragma unroll
  for (int it = 0; it < 2; ++it) {
    int row = w * 32 + it * 16 + (lane >> 2);
    int seg8 = (lane & 3) * 8;
    int rl = m0 + row;
    if (rl >= m_cnt) rl = m_cnt - 1;
    int grow = perm ? perm[m_start + rl] : (m_start + rl);
    agp[it] = A + (size_t)grow * lda + seg8;
    bgp[it] = W + (size_t)(n0 + row) * K + seg8;
    al[it] = As + (w * 32 + it * 16) * 32;
    bl[it] = Bs + (w * 32 + it * 16) * 32;
  }

  const int nk = K >> 5;
#pragma unroll
  for (int it = 0; it < 2; ++it) { async16(agp[it], al[it]); async16(bgp[it], bl[it]); }
  if (nk > 1) {
#pragma unroll
    for (int it = 0; it < 2; ++it) {
      async16(agp[it] + 32, al[it] + 4096);
      async16(bgp[it] + 32, bl[it] + 4096);
    }
  }

  int bk = 0;
  for (int k = 0; k < nk; ++k) {
    int bn = bk + 2; if (bn >= 3) bn -= 3;
    if (k + 2 < nk) {
#pragma unroll
      for (int it = 0; it < 2; ++it) {
        async16(agp[it] + (k + 2) * 32, al[it] + bn * 4096);
        async16(bgp[it] + (k + 2) * 32, bl[it] + bn * 4096);
      }
      asm volatile("s_waitcnt vmcnt(8)" ::: "memory");
    } else if (k + 1 < nk) {
      asm volatile("s_waitcnt vmcnt(4)" ::: "memory");
    } else {
      asm volatile("s_waitcnt vmcnt(0)" ::: "memory");
    }
    asm volatile("s_barrier" ::: "memory");
    const unsigned short* Ab = As + bk * 4096;
    const unsigned short* Bb = Bs + bk * 4096;
    bf16x8 af[4], bfv[4];
#pragma unroll
    for (int i = 0; i < 4; ++i)
      af[i] = *(const bf16x8*)(Ab + (wm * 64 + i * 16 + fr) * 32 + fk);
#pragma unroll
    for (int j = 0; j < 4; ++j)
      bfv[j] = *(const bf16x8*)(Bb + (wn * 64 + j * 16 + fr) * 32 + fk);
    __builtin_amdgcn_s_setprio(1);
#pragma unroll
    for (int i = 0; i < 4; ++i)
#pragma unroll
      for (int j = 0; j < 4; ++j)
        acc[i][j] = __builtin_amdgcn_mfma_f32_16x16x32_bf16(af[i], bfv[j], acc[i][j], 0, 0, 0);
    __builtin_amdgcn_s_setprio(0);
    asm volatile("s_barrier" ::: "memory");
    ++bk; if (bk == 3) bk = 0;
  }

  const int rquad = (lane >> 4) * 4;
  const int cidx = lane & 15;

  float bv[4];
#pragma unroll
  for (int j = 0; j < 4; ++j) bv[j] = bi ? bi[n0 + wn * 64 + j * 16 + cidx] : 0.f;

  unsigned short (*bscr)[136] = (unsigned short(*)[136])dynsm;
#pragma unroll
  for (int c = 0; c < 4; ++c) {
    if (wm == (c >> 1)) {
#pragma unroll
      for (int j = 0; j < 4; ++j) {
#pragma unroll
        for (int ii = 0; ii < 2; ++ii) {
          int i = 2 * (c & 1) + ii;
          int lr = ii * 16 + rquad;
#pragma unroll
          for (int r = 0; r < 4; ++r) {
            float v = acc[i][j][r] + bv[j];
            if (relu) v = fmaxf(v, 0.f);
            bscr[lr + r][wn * 64 + j * 16 + cidx] = f2bf(v);
          }
        }
      }
    }
    __syncthreads();
#pragma unroll
    for (int q = 0; q < 2; ++q) {
      int sg = t + 256 * q;
      int lr = sg >> 4, cs = (sg & 15) * 8;
      int grow = m0 + c * 32 + lr;
      if (grow < m_cnt)
        *(bf16x8*)(C + (size_t)(m_start + grow) * ldc + (n0 + cs)) =
            *(const bf16x8*)(&bscr[lr][cs]);
    }
    __syncthreads();
  }
}

// --- prep: wjbf + transposes + count + b_f PARTIALS ---------------------------
// (feat convert moved to k_mid to overlap with ms/W_f compute.)
struct WSeg { const float* src; unsigned short* dst; int K; int N; int ldd; };
struct PrepArgs {
  WSeg s[12];
  int start[13];
  const float* join_w; unsigned short* wjbf;
  const int* cmd; int* wavecnt;
  const float* join_b; const float* ctrl_w1; float* bf_part;
};
__launch_bounds__(256)
__global__ void k_prep(PrepArgs a) {
  int bx = blockIdx.x, t = threadIdx.x;
  if (bx < 320) {            // ---- join_w straight convert
    int idx = bx * 256 + t;
    float4 f = *(const float4*)(a.join_w + (size_t)idx * 4);
    ushort4 o;
    o.x = f2bf(f.x); o.y = f2bf(f.y); o.z = f2bf(f.z); o.w = f2bf(f.w);
    *(ushort4*)(a.wjbf + (size_t)idx * 4) = o;
    return;
  }
  int rel = bx - 320;
  if (rel < a.start[12]) {   // ---- 32x32 transpose tiles
    __shared__ float tb[32][33];
    int si = 0;
    while (rel >= a.start[si + 1]) ++si;
    WSeg sg = a.s[si];
    int tile = rel - a.start[si];
    int tkx = sg.K >> 5;
    int tn = tile / tkx;
    int tk = tile - tn * tkx;
    int k0 = tk * 32, n0 = tn * 32;
    int tx = t & 31, ty = t >> 5;
#pragma unroll
    for (int j = 0; j < 4; ++j)
      tb[ty + j * 8][tx] = sg.src[(size_t)(k0 + ty + j * 8) * sg.N + n0 + tx];
    __syncthreads();
#pragma unroll
    for (int j = 0; j < 4; ++j)
      sg.dst[(size_t)(n0 + ty + j * 8) * sg.ldd + k0 + tx] = f2bf(tb[tx][ty + j * 8]);
    return;
  }
  rel -= a.start[12];
  if (rel < 128) {           // ---- command count (ballot histogram)
    int i = rel * 256 + t;
    int c = a.cmd[i];
    int wid = i >> 6;
    int lane = t & 63;
#pragma unroll
    for (int cv = 0; cv < NCMD; ++cv) {
      unsigned long long m = __ballot(c == cv);
      if (lane == 0) a.wavecnt[cv * 512 + wid] = __popcll(m);
    }
    return;
  }
  // ---- bf_part[e][ch][n] = sum_{m in [ch*64,(ch+1)*64)} join_b[m]*ctrl_w1[e][m][n]
  int idx = rel - 128;       // 0..31
  int e = idx >> 3, ch = idx & 7;
  const float* w = a.ctrl_w1 + (size_t)e * 512 * 256 + (size_t)ch * 64 * 256 + t;
  const float* jb = a.join_b + ch * 64;
  float s0 = 0.f, s1 = 0.f, s2 = 0.f, s3 = 0.f;
  float s4 = 0.f, s5 = 0.f, s6 = 0.f, s7 = 0.f;
#pragma unroll
  for (int g = 0; g < 8; ++g) {   // 8 independent loads in flight per group
    s0 = fmaf(jb[g * 8 + 0], w[(size_t)(g * 8 + 0) * 256], s0);
    s1 = fmaf(jb[g * 8 + 1], w[(size_t)(g * 8 + 1) * 256], s1);
    s2 = fmaf(jb[g * 8 + 2], w[(size_t)(g * 8 + 2) * 256], s2);
    s3 = fmaf(jb[g * 8 + 3], w[(size_t)(g * 8 + 3) * 256], s3);
    s4 = fmaf(jb[g * 8 + 4], w[(size_t)(g * 8 + 4) * 256], s4);
    s5 = fmaf(jb[g * 8 + 5], w[(size_t)(g * 8 + 5) * 256], s5);
    s6 = fmaf(jb[g * 8 + 6], w[(size_t)(g * 8 + 6) * 256], s6);
    s7 = fmaf(jb[g * 8 + 7], w[(size_t)(g * 8 + 7) * 256], s7);
  }
  a.bf_part[(size_t)(e * 8 + ch) * 256 + t] =
      ((s0 + s1) + (s2 + s3)) + ((s4 + s5) + (s6 + s7));
}

// -- k_mid: place (0..127) + W_f GEMM (128..167) + ms (168..423) + b_f (424..427)
//    + feat f32->bf16 convert (428..16811, dispatched LAST so the BW-bound
//    stream overlaps the compute sections instead of serializing in k_prep).
struct MidArgs {
  const int* cmd; const int* wavecnt; int* perm; int* offs;
  const unsigned short* c_w1t; const unsigned short* wjbf; unsigned short* wf_t;
  const float* speed;
  const float* ms_w1; const float* ms_b1;
  const unsigned short* ms_w2t; const float* ms_b2;
  const unsigned short* ms_w3t; const float* ms_b3;
  const float* feat;
  unsigned short* ajoin;
  const float* bf_part; const float* ctrl_b1; float* b_f;
  int* tile_e; int* tile_r0; int* ntl;
};
__launch_bounds__(256)
__global__ void k_mid(MidArgs a) {
  int b = blockIdx.x, t = threadIdx.x;
  if (b >= 428) {            // ---- feat f32 -> bf16 into ajoin[:,0:512]
    int idx = (b - 428) * 256 + t;
    int i = idx >> 7;
    int j4 = (idx & 127) << 2;
    float4 f = *(const float4*)(a.feat + (size_t)i * FEAT + j4);
    ushort4 o;
    o.x = f2bf(f.x); o.y = f2bf(f.y); o.z = f2bf(f.z); o.w = f2bf(f.w);
    *(ushort4*)(a.ajoin + (size_t)i * 640 + j4) = o;
    return;
  }
  if (b >= 424) {            // ---- b_f reduce
    int e = b - 424;
    float s = a.ctrl_b1[e * 256 + t];
#pragma unroll
    for (int ch = 0; ch < 8; ++ch) s += a.bf_part[(size_t)(e * 8 + ch) * 256 + t];
    a.b_f[e * 256 + t] = s;
    return;
  }
  if (b >= 168) {            // ---- measured-speed module (MFMA, LDS-resident)
    extern __shared__ __align__(16) unsigned char dynsm[];
    unsigned short (*hw)[136] = (unsigned short(*)[136])dynsm;
    unsigned short* BsM = (unsigned short*)(dynsm + 128 * 136 * 2);
    const int m0 = (b - 168) * 128;
    const int w = t >> 6, lane = t & 63;
    const int wm = w & 1, wn = w >> 1;
    const int fr = lane & 15, fk = (lane >> 4) * 8;
    const int rquad = (lane >> 4) * 4, cidx = lane & 15;
    {
      int r = t >> 1, half = t & 1;
      float s = a.speed[m0 + r];
#pragma unroll
      for (int c0 = 0; c0 < 64; c0 += 4) {
        int c = half * 64 + c0;
        float4 wv = *(const float4*)(a.ms_w1 + c);
        float4 bv = *(const float4*)(a.ms_b1 + c);
        hw[r][c + 0] = f2bf(fmaxf(fmaf(s, wv.x, bv.x), 0.f));
        hw[r][c + 1] = f2bf(fmaxf(fmaf(s, wv.y, bv.y), 0.f));
        hw[r][c + 2] = f2bf(fmaxf(fmaf(s, wv.z, bv.z), 0.f));
        hw[r][c + 3] = f2bf(fmaxf(fmaf(s, wv.w, bv.w), 0.f));
      }
    }
    __syncthreads();
    for (int layer = 0; layer < 2; ++layer) {
      const unsigned short* Wt = layer ? a.ms_w3t : a.ms_w2t;
      const float* bb = layer ? a.ms_b3 : a.ms_b2;
      f32x4 acc[4][4];
#pragma unroll
      for (int i = 0; i < 4; ++i)
#pragma unroll
        for (int j = 0; j < 4; ++j)
#pragma unroll
          for (int r = 0; r < 4; ++r) acc[i][j][r] = 0.f;
      for (int k0 = 0; k0 < 128; k0 += 32) {
#pragma unroll
        for (int it = 0; it < 2; ++it) {
          int row = w * 32 + it * 16 + (lane >> 2);
          async16(Wt + (size_t)row * 128 + k0 + (lane & 3) * 8,
                  BsM + (w * 32 + it * 16) * 32);
        }
        __syncthreads();
        bf16x8 af[4], bfv[4];
#pragma unroll
        for (int i = 0; i < 4; ++i)
          af[i] = *(const bf16x8*)(&hw[wm * 64 + i * 16 + fr][k0 + fk]);
#pragma unroll
        for (int j = 0; j < 4; ++j)
          bfv[j] = *(const bf16x8*)(BsM + (wn * 64 + j * 16 + fr) * 32 + fk);
#pragma unroll
        for (int i = 0; i < 4; ++i)
#pragma unroll
          for (int j = 0; j < 4; ++j)
            acc[i][j] = __builtin_amdgcn_mfma_f32_16x16x32_bf16(af[i], bfv[j], acc[i][j], 0, 0, 0);
        __syncthreads();
      }
#pragma unroll
      for (int j = 0; j < 4; ++j) {
        int col = wn * 64 + j * 16 + cidx;
        float bv = bb[col];
#pragma unroll
        for (int i = 0; i < 4; ++i) {
          int row = wm * 64 + i * 16 + rquad;
#pragma unroll
          for (int r = 0; r < 4; ++r) {
            float v = acc[i][j][r] + bv;
            if (layer == 0) v = fmaxf(v, 0.f);
            hw[row + r][col] = f2bf(v);
          }
        }
      }
      __syncthreads();
    }
    {
      int r = t >> 1, half = t & 1;
#pragma unroll
      for (int c8 = 0; c8 < 8; ++c8)
        *(bf16x8*)(a.ajoin + (size_t)(m0 + r) * 640 + 512 + half * 64 + c8 * 8) =
            *(const bf16x8*)(&hw[r][half * 64 + c8 * 8]);
    }
    return;
  }
  if (b >= 128) {            // ---- W_f fuse GEMM (depth-2 pipelined)
    int idx = b - 128;                 // 0..39
    int mt = idx & 7, nt = idx >> 3;   // M=1024 -> 8 mtiles, N=640 -> 5 ntiles
    gemm128_db(a.c_w1t, 512, nullptr, 0, 1024, a.wjbf, nullptr, a.wf_t, 640, 0, 512, mt, nt);
    return;
  }
  // ---- place with per-block self-scan
  __shared__ int pf[NCMD][4];
  __shared__ int tot[NCMD];
  int c = t >> 6, lane = t & 63;
  int v[8]; int s = 0;
#pragma unroll
  for (int q = 0; q < 8; ++q) { v[q] = a.wavecnt[c * 512 + lane * 8 + q]; s += v[q]; }
  int p = s;
#pragma unroll
  for (int m = 1; m < 64; m <<= 1) { int o = __shfl_up(p, m, 64); if (lane >= m) p += o; }
  int excl = p - s;
  if (lane == 63) tot[c] = p;
  if (lane == ((4 * b) >> 3)) {
    int base_off = (4 * b) & 7;
    int run = excl;
#pragma unroll
    for (int q = 0; q < 8; ++q) {
      if (q >= base_off && q < base_off + 4) pf[c][q - base_off] = run;
      run += v[q];
    }
  }
  __syncthreads();
  int soffs[NCMD + 1];
  soffs[0] = 0;
#pragma unroll
  for (int e = 0; e < NCMD; ++e) soffs[e + 1] = soffs[e] + tot[e];
  if (b == 0 && t == 0)
    for (int e = 0; e <= NCMD; ++e) a.offs[e] = soffs[e];
  int i = b * 256 + t;
  int mc = a.cmd[i];
  int lwid = t >> 6;
  int rank = 0, base = 0;
#pragma unroll
  for (int cv = 0; cv < NCMD; ++cv) {
    unsigned long long m = __ballot(mc == cv);
    if (mc == cv) {
      rank = __popcll(m & ((1ull << lane) - 1ull));
      base = soffs[cv] + pf[cv][lwid];
    }
  }
  a.perm[base + rank] = i;

  // ---- 128-row tile table for k_main ctrl path (block 0 only)
  if (b == 0) {
    int toff[NCMD + 1];
    toff[0] = 0;
#pragma unroll
    for (int ee = 0; ee < NCMD; ++ee) toff[ee + 1] = toff[ee] + ((tot[ee] + 127) >> 7);
    if (t == 0) a.ntl[0] = toff[NCMD];
    for (int ti = t; ti < toff[NCMD]; ti += 256) {
      int ee = 0;
      while (ti >= toff[ee + 1]) ++ee;
      a.tile_e[ti] = ee;
      a.tile_r0[ti] = soffs[ee] + (ti - toff[ee]) * 128;
    }
  }
}

// ---- k_main (R6-proven): z<2 -> ctrl1 (128-row tile table, perm-gathered,
// nt=z); z in {2,3} -> sp1 on NATURAL rows (nt=z-2), sph1 un-permuted.
struct MainArgs {
  const unsigned short* ajoin;
  const unsigned short* wf_t; const float* b_f;
  const unsigned short* sp_w1t; const float* sp_b1;
  unsigned short* ch1; unsigned short* sph1;
  const int* perm; const int* seg;
  const int* tile_e; const int* tile_r0; const int* ntl;
};
__launch_bounds__(256)
__global__ void k_main(MainArgs a) {
  const int z = blockIdx.z;
  if (z < 2) {
    int ti = blockIdx.x;
    if (ti >= a.ntl[0]) return;
    int e = a.tile_e[ti];
    int r0 = a.tile_r0[ti];
    int mc = a.seg[e + 1] - r0; if (mc > 128) mc = 128;
    gemm128_db(a.ajoin, 640, a.perm, r0, mc, a.wf_t + (size_t)e * 256 * 640,
               a.b_f + e * 256, a.ch1, 256, 1, 640, 0, z);
  } else {
    int mt = blockIdx.x;
    if (mt >= 256) return;
    gemm128_db(a.ajoin, 640, nullptr, 0, BB, a.sp_w1t, a.sp_b1,
               a.sph1, 256, 1, 512, mt, z - 2);
  }
}

// ------- k_vgemm: 64xN256 GEMM + exact final dot; depth-1 counted vmcnt ------
struct VArgs {
  const unsigned short* A_s; const unsigned short* A_c;
  const unsigned short* W_s; const unsigned short* W_c;
  const float* b_s; const float* b_c;
  const float* w3_s; const float* b3_s;
  const float* w3_c; const float* b3_c;
  const int* perm; const int* seg;
  float* out;
};
__launch_bounds__(256)
__global__ void k_vgemm(VArgs a) {
  __shared__ unsigned short As[2 * 64 * 32];    //  8 KB, 2 bufs
  __shared__ unsigned short Bs[2 * 256 * 32];   // 32 KB, 2 bufs
  const int z = blockIdx.z;
  const unsigned short* A; const unsigned short* W; const float* bi;
  int m_start, m_cnt;
  if (z == 4) { A = a.A_s; W = a.W_s; bi = a.b_s; m_start = 0; m_cnt = BB; }
  else {
    A = a.A_c; W = a.W_c + (size_t)z * 65536; bi = a.b_c + z * 256;
    m_start = a.seg[z]; m_cnt = a.seg[z + 1] - m_start;
  }
  const int m0 = blockIdx.x * 64;
  if (m0 >= m_cnt) return;
  const int t = threadIdx.x, w = t >> 6, lane = t & 63;
  const int fr = lane & 15, fk = (lane >> 4) * 8;

  f32x4 acc[16];
#pragma unroll
  for (int j = 0; j < 16; ++j)
#pragma unroll
    for (int r = 0; r < 4; ++r) acc[j][r] = 0.f;

  int arow = m0 + w * 16 + (lane >> 2);
  if (arow >= m_cnt) arow = m_cnt - 1;
  const unsigned short* ap = A + (size_t)(m_start + arow) * 256 + (lane & 3) * 8;
  unsigned short* al = As + (w * 16) * 32;
  const unsigned short* bp[4]; unsigned short* bl[4];
#pragma unroll
  for (int it = 0; it < 4; ++it) {
    int brow = w * 64 + it * 16 + (lane >> 2);
    bp[it] = W + (size_t)brow * 256 + (lane & 3) * 8;
    bl[it] = Bs + (w * 64 + it * 16) * 32;
  }

  // prologue: chunk 0 -> buf 0 (5 asyncs per lane)
  async16(ap, al);
#pragma unroll
  for (int it = 0; it < 4; ++it) async16(bp[it], bl[it]);

  for (int k = 0; k < 8; ++k) {
    const int cur = (k & 1) * 2048, curB = (k & 1) * 8192;
    if (k + 1 < 8) {
      const int nxt = ((k + 1) & 1) * 2048, nxtB = ((k + 1) & 1) * 8192;
      async16(ap + (k + 1) * 32, al + nxt);
#pragma unroll
      for (int it = 0; it < 4; ++it) async16(bp[it] + (k + 1) * 32, bl[it] + nxtB);
      asm volatile("s_waitcnt vmcnt(5)" ::: "memory");   // chunk k landed
    } else {
      asm volatile("s_waitcnt vmcnt(0)" ::: "memory");
    }
    asm volatile("s_barrier" ::: "memory");
    bf16x8 af = *(const bf16x8*)(As + cur + (w * 16 + fr) * 32 + fk);
    __builtin_amdgcn_s_setprio(1);
#pragma unroll
    for (int j = 0; j < 16; ++j) {
      bf16x8 bfv = *(const bf16x8*)(Bs + curB + (j * 16 + fr) * 32 + fk);
      acc[j] = __builtin_amdgcn_mfma_f32_16x16x32_bf16(af, bfv, acc[j], 0, 0, 0);
    }
    __builtin_amdgcn_s_setprio(0);
    asm volatile("s_barrier" ::: "memory");
  }

  const int rquad = (lane >> 4) * 4;
  float bcol[16];
#pragma unroll
  for (int j = 0; j < 16; ++j) bcol[j] = bi[j * 16 + fr];

  if (z == 4) {
    float aw[16];
#pragma unroll
    for (int j = 0; j < 16; ++j) aw[j] = a.w3_s[j * 16 + fr];
#pragma unroll
    for (int r = 0; r < 4; ++r) {
      float s = 0.f;
#pragma unroll
      for (int j = 0; j < 16; ++j)
        s = fmaf(fmaxf(acc[j][r] + bcol[j], 0.f), aw[j], s);
      s += __shfl_xor(s, 1, 64);
      s += __shfl_xor(s, 2, 64);
      s += __shfl_xor(s, 4, 64);
      s += __shfl_xor(s, 8, 64);
      int row = m0 + w * 16 + rquad + r;
      if (fr == 0 && row < m_cnt)
        a.out[row] = s + a.b3_s[0];                 // sph1 natural -> direct
    }
  } else {
    float aw0[16], aw1[16], aw2[16];
#pragma unroll
    for (int j = 0; j < 16; ++j) {
      const float* wp = a.w3_c + (size_t)z * 768 + (j * 16 + fr) * 3;
      aw0[j] = wp[0]; aw1[j] = wp[1]; aw2[j] = wp[2];
    }
#pragma unroll
    for (int r = 0; r < 4; ++r) {
      float s0 = 0.f, s1 = 0.f, s2 = 0.f;
#pragma unroll
      for (int j = 0; j < 16; ++j) {
        float v = fmaxf(acc[j][r] + bcol[j], 0.f);
        s0 = fmaf(v, aw0[j], s0);
        s1 = fmaf(v, aw1[j], s1);
        s2 = fmaf(v, aw2[j], s2);
      }
#pragma unroll
      for (int m = 1; m <= 8; m <<= 1) {
        s0 += __shfl_xor(s0, m, 64);
        s1 += __shfl_xor(s1, m, 64);
        s2 += __shfl_xor(s2, m, 64);
      }
      int row = m0 + w * 16 + rquad + r;
      if (fr == 0 && row < m_cnt) {
        int orig = a.perm[m_start + row];
        float a0 = s0 + a.b3_c[z * 3 + 0];
        float a1 = s1 + a.b3_c[z * 3 + 1];
        float a2 = s2 + a.b3_c[z * 3 + 2];
        a.out[BB + orig]     = 1.f / (1.f + __expf(-a0));   // throttle
        a.out[2 * BB + orig] = 1.f / (1.f + __expf(-a2));   // brake
        a.out[3 * BB + orig] = tanhf(a1);                   // steering
      }
    }
  }
}

static inline size_t align256(size_t x) { return (x + 255) & ~(size_t)255; }

extern "C" void kernel_launch(void* const* d_in, const int* in_sizes, int n_in,
                              void* d_out, int out_size, void* d_ws, size_t ws_size,
                              hipStream_t stream) {
  const float* feat   = (const float*)d_in[0];
  const float* speed  = (const float*)d_in[1];
  const int*   command= (const int*)d_in[2];
  const float* ms_w1  = (const float*)d_in[3];
  const float* ms_b1  = (const float*)d_in[4];
  const float* ms_w2  = (const float*)d_in[5];
  const float* ms_b2  = (const float*)d_in[6];
  const float* ms_w3  = (const float*)d_in[7];
  const float* ms_b3  = (const float*)d_in[8];
  const float* sp_w1  = (const float*)d_in[9];
  const float* sp_b1  = (const float*)d_in[10];
  const float* sp_w2  = (const float*)d_in[11];
  const float* sp_b2  = (const float*)d_in[12];
  const float* sp_w3  = (const float*)d_in[13];
  const float* sp_b3  = (const float*)d_in[14];
  const float* join_w = (const float*)d_in[15];
  const float* join_b = (const float*)d_in[16];
  const float* ctrl_w1= (const float*)d_in[17];
  const float* ctrl_b1= (const float*)d_in[18];
  const float* ctrl_w2= (const float*)d_in[19];
  const float* ctrl_b2= (const float*)d_in[20];
  const float* ctrl_w3= (const float*)d_in[21];
  const float* ctrl_b3= (const float*)d_in[22];
  float* out = (float*)d_out;

  char* ws = (char*)d_ws;
  size_t off = 0;
  auto alloc = [&](size_t bytes) -> char* { char* p = ws + off; off = align256(off + bytes); return p; };

  unsigned short* ajoin  = (unsigned short*)alloc((size_t)BB * 640 * 2);
  unsigned short* sph1   = (unsigned short*)alloc((size_t)BB * 256 * 2);
  unsigned short* ch1    = (unsigned short*)alloc((size_t)BB * 256 * 2);
  unsigned short* wtp    = (unsigned short*)alloc(1998848ull * 2);
  int* perm    = (int*)alloc((size_t)BB * 4);
  int* cnt     = (int*)alloc(64);        // offs[5] at cnt+4
  int* wavecnt = (int*)alloc(4 * 512 * 4);
  float* bf_part = (float*)alloc(4 * 8 * 256 * 4);
  float* b_f   = (float*)alloc(4 * 256 * 4);
  int* tile_e  = (int*)alloc(272 * 4);
  int* tile_r0 = (int*)alloc(272 * 4);
  int* ntl     = (int*)alloc(64);

  unsigned short* sp_w1t = wtp;                 // [256][512]
  unsigned short* sp_w2t = wtp + 131072;        // [256][256]
  unsigned short* ms_w2t = wtp + 196608;        // [128][128]
  unsigned short* ms_w3t = wtp + 212992;        // [128][128]
  unsigned short* c_w1t  = wtp + 229376;        // [4][256][512]
  unsigned short* c_w2t  = wtp + 753664;        // [4][256][256]
  unsigned short* wjbf   = wtp + 1015808;       // [640][512] straight bf16
  unsigned short* wf_t   = wtp + 1343488;       // [4][256][640] fused W_f^T

  PrepArgs P;
  P.s[0] = { sp_w1, sp_w1t, 512, 256, 512 };
  P.s[1] = { sp_w2, sp_w2t, 256, 256, 256 };
  P.s[2] = { ms_w2, ms_w2t, 128, 128, 128 };
  P.s[3] = { ms_w3, ms_w3t, 128, 128, 128 };
  for (int e = 0; e < 4; ++e) P.s[4 + e] = { ctrl_w1 + (size_t)e * 512 * 256, c_w1t + (size_t)e * 131072, 512, 256, 512 };
  for (int e = 0; e < 4; ++e) P.s[8 + e] = { ctrl_w2 + (size_t)e * 256 * 256, c_w2t + (size_t)e * 65536, 256, 256, 256 };
  P.start[0] = 0;
  for (int i = 0; i < 12; ++i)
    P.start[i + 1] = P.start[i] + (P.s[i].K >> 5) * (P.s[i].N >> 5);
  P.join_w = join_w; P.wjbf = wjbf;
  P.cmd = command; P.wavecnt = wavecnt;
  P.join_b = join_b; P.ctrl_w1 = ctrl_w1; P.bf_part = bf_part;
  int prep_blocks = 320 + P.start[12] + 128 + 32;

  k_prep<<<prep_blocks, 256, 0, stream>>>(P);

  MidArgs Mi;
  Mi.cmd = command; Mi.wavecnt = wavecnt; Mi.perm = perm; Mi.offs = cnt + 4;
  Mi.c_w1t = c_w1t; Mi.wjbf = wjbf; Mi.wf_t = wf_t;
  Mi.speed = speed;
  Mi.ms_w1 = ms_w1; Mi.ms_b1 = ms_b1;
  Mi.ms_w2t = ms_w2t; Mi.ms_b2 = ms_b2;
  Mi.ms_w3t = ms_w3t; Mi.ms_b3 = ms_b3;
  Mi.feat = feat;
  Mi.ajoin = ajoin;
  Mi.bf_part = bf_part; Mi.ctrl_b1 = ctrl_b1; Mi.b_f = b_f;
  Mi.tile_e = tile_e; Mi.tile_r0 = tile_r0; Mi.ntl = ntl;
  // blocks: 428 compute sections first, then 16384 feat-convert (overlapped)
  k_mid<<<428 + 16384, 256, 49152, stream>>>(Mi);

  MainArgs Ma;
  Ma.ajoin = ajoin; Ma.wf_t = wf_t; Ma.b_f = b_f;
  Ma.sp_w1t = sp_w1t; Ma.sp_b1 = sp_b1;
  Ma.ch1 = ch1; Ma.sph1 = sph1;
  Ma.perm = perm; Ma.seg = cnt + 4;
  Ma.tile_e = tile_e; Ma.tile_r0 = tile_r0; Ma.ntl = ntl;
  // x: ctrl tiles <= 259 (z<2), sp mtiles = 256 (z in {2,3}); 48 KB dyn LDS
  k_main<<<dim3(260, 1, 4), 256, 49152, stream>>>(Ma);

  VArgs V;
  V.A_s = sph1; V.A_c = ch1; V.W_s = sp_w2t; V.W_c = c_w2t;
  V.b_s = sp_b2; V.b_c = ctrl_b2;
  V.w3_s = sp_w3; V.b3_s = sp_b3; V.w3_c = ctrl_w3; V.b3_c = ctrl_b3;
  V.perm = perm; V.seg = cnt + 4; V.out = out;
  k_vgemm<<<dim3(512, 1, 5), 256, 0, stream>>>(V);
}

// Round 11
// 222.693 us; speedup vs baseline: 1.0441x; 1.0441x over previous
//
#include <hip/hip_runtime.h>
#include <hip/hip_bf16.h>
#include <stdint.h>
#include <math.h>

#define BB 32768
#define FEAT 512
#define SPD_H 128
#define CTRL_H 256
#define NCMD 4

typedef __attribute__((ext_vector_type(8))) short bf16x8;
typedef __attribute__((ext_vector_type(4))) float f32x4;

__device__ __forceinline__ unsigned short f2bf(float f) {
  union { float f; uint32_t u; } v; v.f = f;
  uint32_t u = v.u;
  return (unsigned short)((u + 0x7fffu + ((u >> 16) & 1u)) >> 16); // RNE
}

// async global->LDS, 16B per lane; LDS dest = wave-uniform base + lane*16
__device__ __forceinline__ void async16(const unsigned short* g, unsigned short* l) {
  __builtin_amdgcn_global_load_lds(
      (const __attribute__((address_space(1))) unsigned int*)g,
      (__attribute__((address_space(3))) unsigned int*)l, 16, 0, 0);
}

// T2 swizzle for [row][32-short] staging tiles (64B rows = 4x16B slots).
// Store: LDS slot s of row r holds k-segment s ^ ((r>>1)&3), achieved by
// pre-swizzling the GLOBAL source per lane (rule 21; DMA dest stays linear):
// lane l loads segment (l&3) ^ ((l>>3)&3)  [r_local = l>>2].
// Read: slot = fcg ^ ((row>>1)&3); rows are X*16+fr so (row>>1)&3 = (fr>>1)&3.
// Spreads the 16 fr-lanes' b128 windows over all 32 banks (2 lanes/bank =
// free); linear layout put them on 8 banks (SQ_LDS_BANK_CONFLICT 2.5M).
#define SRC_SEG(lane) ((((lane) & 3) ^ (((lane) >> 3) & 3)) * 8)
#define RD_SLOT(lane) (((((lane) >> 4) ^ (((lane) >> 1) & 3))) * 8)

// ------- 128x128 bf16 MFMA GEMM tile, depth-2 counted-vmcnt pipeline ---------
// T3/T4: 3 LDS buffers; chunk k+2 issued while chunk k computes; s_waitcnt
// vmcnt(8) + raw s_barrier pair (FIFO completion => counts safe even with
// stray VMEM: chunk k's asyncs are always older than the 8 newest).
// T5 setprio around the MFMA cluster. 48 KB dynamic LDS.
__device__ __forceinline__ void gemm128_db(
    const unsigned short* __restrict__ A, int lda,
    const int* __restrict__ perm, int m_start, int m_cnt,
    const unsigned short* __restrict__ W, const float* __restrict__ bi,
    unsigned short* __restrict__ C, int ldc, int relu, int K, int mt, int nt) {
  extern __shared__ __align__(16) unsigned char dynsm[];
  unsigned short* As = (unsigned short*)dynsm;     // 3 bufs x [128][32]
  unsigned short* Bs = As + 3 * 4096;              // 3 bufs x [128][32]

  const int m0 = mt * 128;
  if (m0 >= m_cnt) return;
  const int n0 = nt * 128;
  const int t = threadIdx.x;
  const int w = t >> 6, lane = t & 63;
  const int wm = w & 1, wn = w >> 1;

  f32x4 acc[4][4];
#pragma unroll
  for (int i = 0; i < 4; ++i)
#pragma unroll
    for (int j = 0; j < 4; ++j)
#pragma unroll
      for (int r = 0; r < 4; ++r) acc[i][j][r] = 0.f;

  const int fr = lane & 15;
  const int fk = RD_SLOT(lane);

  const unsigned short* agp[2]; const unsigned short* bgp[2];
  unsigned short* al[2]; unsigned short* bl[2];
#pragma unroll
  for (int it = 0; it < 2; ++it) {
    int row = w * 32 + it * 16 + (lane >> 2);
    int seg8 = SRC_SEG(lane);
    int rl = m0 + row;
    if (rl >= m_cnt) rl = m_cnt - 1;
    int grow = perm ? perm[m_start + rl] : (m_start + rl);
    agp[it] = A + (size_t)grow * lda + seg8;
    bgp[it] = W + (size_t)(n0 + row) * K + seg8;
    al[it] = As + (w * 32 + it * 16) * 32;
    bl[it] = Bs + (w * 32 + it * 16) * 32;
  }

  const int nk = K >> 5;
#pragma unroll
  for (int it = 0; it < 2; ++it) { async16(agp[it], al[it]); async16(bgp[it], bl[it]); }
  if (nk > 1) {
#pragma unroll
    for (int it = 0; it < 2; ++it) {
      async16(agp[it] + 32, al[it] + 4096);
      async16(bgp[it] + 32, bl[it] + 4096);
    }
  }

  int bk = 0;
  for (int k = 0; k < nk; ++k) {
    int bn = bk + 2; if (bn >= 3) bn -= 3;
    if (k + 2 < nk) {
#pragma unroll
      for (int it = 0; it < 2; ++it) {
        async16(agp[it] + (k + 2) * 32, al[it] + bn * 4096);
        async16(bgp[it] + (k + 2) * 32, bl[it] + bn * 4096);
      }
      asm volatile("s_waitcnt vmcnt(8)" ::: "memory");
    } else if (k + 1 < nk) {
      asm volatile("s_waitcnt vmcnt(4)" ::: "memory");
    } else {
      asm volatile("s_waitcnt vmcnt(0)" ::: "memory");
    }
    asm volatile("s_barrier" ::: "memory");
    const unsigned short* Ab = As + bk * 4096;
    const unsigned short* Bb = Bs + bk * 4096;
    bf16x8 af[4], bfv[4];
#pragma unroll
    for (int i = 0; i < 4; ++i)
      af[i] = *(const bf16x8*)(Ab + (wm * 64 + i * 16 + fr) * 32 + fk);
#pragma unroll
    for (int j = 0; j < 4; ++j)
      bfv[j] = *(const bf16x8*)(Bb + (wn * 64 + j * 16 + fr) * 32 + fk);
    __builtin_amdgcn_s_setprio(1);
#pragma unroll
    for (int i = 0; i < 4; ++i)
#pragma unroll
      for (int j = 0; j < 4; ++j)
        acc[i][j] = __builtin_amdgcn_mfma_f32_16x16x32_bf16(af[i], bfv[j], acc[i][j], 0, 0, 0);
    __builtin_amdgcn_s_setprio(0);
    asm volatile("s_barrier" ::: "memory");
    ++bk; if (bk == 3) bk = 0;
  }

  const int rquad = (lane >> 4) * 4;
  const int cidx = lane & 15;

  float bv[4];
#pragma unroll
  for (int j = 0; j < 4; ++j) bv[j] = bi ? bi[n0 + wn * 64 + j * 16 + cidx] : 0.f;

  unsigned short (*bscr)[136] = (unsigned short(*)[136])dynsm;
#pragma unroll
  for (int c = 0; c < 4; ++c) {
    if (wm == (c >> 1)) {
#pragma unroll
      for (int j = 0; j < 4; ++j) {
#pragma unroll
        for (int ii = 0; ii < 2; ++ii) {
          int i = 2 * (c & 1) + ii;
          int lr = ii * 16 + rquad;
#pragma unroll
          for (int r = 0; r < 4; ++r) {
            float v = acc[i][j][r] + bv[j];
            if (relu) v = fmaxf(v, 0.f);
            bscr[lr + r][wn * 64 + j * 16 + cidx] = f2bf(v);
          }
        }
      }
    }
    __syncthreads();
#pragma unroll
    for (int q = 0; q < 2; ++q) {
      int sg = t + 256 * q;
      int lr = sg >> 4, cs = (sg & 15) * 8;
      int grow = m0 + c * 32 + lr;
      if (grow < m_cnt)
        *(bf16x8*)(C + (size_t)(m_start + grow) * ldc + (n0 + cs)) =
            *(const bf16x8*)(&bscr[lr][cs]);
    }
    __syncthreads();
  }
}

// --- prep: feat convert + wjbf + transposes + count + b_f PARTIALS ------------
// (feat section is the R6-proven 16384-thin-block form.)
struct WSeg { const float* src; unsigned short* dst; int K; int N; int ldd; };
struct PrepArgs {
  WSeg s[12];
  int start[13];
  const float* join_w; unsigned short* wjbf;
  const float* feat; unsigned short* ajoin;
  const int* cmd; int* wavecnt;
  const float* join_b; const float* ctrl_w1; float* bf_part;
};
__launch_bounds__(256)
__global__ void k_prep(PrepArgs a) {
  int bx = blockIdx.x, t = threadIdx.x;
  if (bx < 16384) {          // ---- feat f32 -> bf16 into ajoin[:,0:512]
    int idx = bx * 256 + t;
    int i = idx >> 7;
    int j4 = (idx & 127) << 2;
    float4 f = *(const float4*)(a.feat + (size_t)i * FEAT + j4);
    ushort4 o;
    o.x = f2bf(f.x); o.y = f2bf(f.y); o.z = f2bf(f.z); o.w = f2bf(f.w);
    *(ushort4*)(a.ajoin + (size_t)i * 640 + j4) = o;
    return;
  }
  int rel = bx - 16384;
  if (rel < 320) {           // ---- join_w straight convert
    int idx = rel * 256 + t;
    float4 f = *(const float4*)(a.join_w + (size_t)idx * 4);
    ushort4 o;
    o.x = f2bf(f.x); o.y = f2bf(f.y); o.z = f2bf(f.z); o.w = f2bf(f.w);
    *(ushort4*)(a.wjbf + (size_t)idx * 4) = o;
    return;
  }
  rel -= 320;
  if (rel < a.start[12]) {   // ---- 32x32 transpose tiles
    __shared__ float tb[32][33];
    int si = 0;
    while (rel >= a.start[si + 1]) ++si;
    WSeg sg = a.s[si];
    int tile = rel - a.start[si];
    int tkx = sg.K >> 5;
    int tn = tile / tkx;
    int tk = tile - tn * tkx;
    int k0 = tk * 32, n0 = tn * 32;
    int tx = t & 31, ty = t >> 5;
#pragma unroll
    for (int j = 0; j < 4; ++j)
      tb[ty + j * 8][tx] = sg.src[(size_t)(k0 + ty + j * 8) * sg.N + n0 + tx];
    __syncthreads();
#pragma unroll
    for (int j = 0; j < 4; ++j)
      sg.dst[(size_t)(n0 + ty + j * 8) * sg.ldd + k0 + tx] = f2bf(tb[tx][ty + j * 8]);
    return;
  }
  rel -= a.start[12];
  if (rel < 128) {           // ---- command count (ballot histogram)
    int i = rel * 256 + t;
    int c = a.cmd[i];
    int wid = i >> 6;
    int lane = t & 63;
#pragma unroll
    for (int cv = 0; cv < NCMD; ++cv) {
      unsigned long long m = __ballot(c == cv);
      if (lane == 0) a.wavecnt[cv * 512 + wid] = __popcll(m);
    }
    return;
  }
  // ---- bf_part[e][ch][n] = sum_{m in [ch*64,(ch+1)*64)} join_b[m]*ctrl_w1[e][m][n]
  int idx = rel - 128;       // 0..31
  int e = idx >> 3, ch = idx & 7;
  const float* w = a.ctrl_w1 + (size_t)e * 512 * 256 + (size_t)ch * 64 * 256 + t;
  const float* jb = a.join_b + ch * 64;
  float s0 = 0.f, s1 = 0.f, s2 = 0.f, s3 = 0.f;
  float s4 = 0.f, s5 = 0.f, s6 = 0.f, s7 = 0.f;
#pragma unroll
  for (int g = 0; g < 8; ++g) {   // 8 independent loads in flight per group
    s0 = fmaf(jb[g * 8 + 0], w[(size_t)(g * 8 + 0) * 256], s0);
    s1 = fmaf(jb[g * 8 + 1], w[(size_t)(g * 8 + 1) * 256], s1);
    s2 = fmaf(jb[g * 8 + 2], w[(size_t)(g * 8 + 2) * 256], s2);
    s3 = fmaf(jb[g * 8 + 3], w[(size_t)(g * 8 + 3) * 256], s3);
    s4 = fmaf(jb[g * 8 + 4], w[(size_t)(g * 8 + 4) * 256], s4);
    s5 = fmaf(jb[g * 8 + 5], w[(size_t)(g * 8 + 5) * 256], s5);
    s6 = fmaf(jb[g * 8 + 6], w[(size_t)(g * 8 + 6) * 256], s6);
    s7 = fmaf(jb[g * 8 + 7], w[(size_t)(g * 8 + 7) * 256], s7);
  }
  a.bf_part[(size_t)(e * 8 + ch) * 256 + t] =
      ((s0 + s1) + (s2 + s3)) + ((s4 + s5) + (s6 + s7));
}

// -- k_mid: place (0..127) + W_f GEMM (128..167) + ms (168..423) + b_f (424..427)
struct MidArgs {
  const int* cmd; const int* wavecnt; int* perm; int* offs;
  const unsigned short* c_w1t; const unsigned short* wjbf; unsigned short* wf_t;
  const float* speed;
  const float* ms_w1; const float* ms_b1;
  const unsigned short* ms_w2t; const float* ms_b2;
  const unsigned short* ms_w3t; const float* ms_b3;
  unsigned short* ajoin;
  const float* bf_part; const float* ctrl_b1; float* b_f;
  int* tile_e; int* tile_r0; int* ntl;
};
__launch_bounds__(256)
__global__ void k_mid(MidArgs a) {
  int b = blockIdx.x, t = threadIdx.x;
  if (b >= 424) {            // ---- b_f reduce
    int e = b - 424;
    float s = a.ctrl_b1[e * 256 + t];
#pragma unroll
    for (int ch = 0; ch < 8; ++ch) s += a.bf_part[(size_t)(e * 8 + ch) * 256 + t];
    a.b_f[e * 256 + t] = s;
    return;
  }
  if (b >= 168) {            // ---- measured-speed module (MFMA, LDS-resident)
    extern __shared__ __align__(16) unsigned char dynsm[];
    unsigned short (*hw)[136] = (unsigned short(*)[136])dynsm;
    unsigned short* BsM = (unsigned short*)(dynsm + 128 * 136 * 2);
    const int m0 = (b - 168) * 128;
    const int w = t >> 6, lane = t & 63;
    const int wm = w & 1, wn = w >> 1;
    const int fr = lane & 15, fk = (lane >> 4) * 8;
    const int rquad = (lane >> 4) * 4, cidx = lane & 15;
    {
      int r = t >> 1, half = t & 1;
      float s = a.speed[m0 + r];
#pragma unroll
      for (int c0 = 0; c0 < 64; c0 += 4) {
        int c = half * 64 + c0;
        float4 wv = *(const float4*)(a.ms_w1 + c);
        float4 bv = *(const float4*)(a.ms_b1 + c);
        hw[r][c + 0] = f2bf(fmaxf(fmaf(s, wv.x, bv.x), 0.f));
        hw[r][c + 1] = f2bf(fmaxf(fmaf(s, wv.y, bv.y), 0.f));
        hw[r][c + 2] = f2bf(fmaxf(fmaf(s, wv.z, bv.z), 0.f));
        hw[r][c + 3] = f2bf(fmaxf(fmaf(s, wv.w, bv.w), 0.f));
      }
    }
    __syncthreads();
    for (int layer = 0; layer < 2; ++layer) {
      const unsigned short* Wt = layer ? a.ms_w3t : a.ms_w2t;
      const float* bb = layer ? a.ms_b3 : a.ms_b2;
      f32x4 acc[4][4];
#pragma unroll
      for (int i = 0; i < 4; ++i)
#pragma unroll
        for (int j = 0; j < 4; ++j)
#pragma unroll
          for (int r = 0; r < 4; ++r) acc[i][j][r] = 0.f;
      for (int k0 = 0; k0 < 128; k0 += 32) {
#pragma unroll
        for (int it = 0; it < 2; ++it) {
          int row = w * 32 + it * 16 + (lane >> 2);
          async16(Wt + (size_t)row * 128 + k0 + (lane & 3) * 8,
                  BsM + (w * 32 + it * 16) * 32);
        }
        __syncthreads();
        bf16x8 af[4], bfv[4];
#pragma unroll
        for (int i = 0; i < 4; ++i)
          af[i] = *(const bf16x8*)(&hw[wm * 64 + i * 16 + fr][k0 + fk]);
#pragma unroll
        for (int j = 0; j < 4; ++j)
          bfv[j] = *(const bf16x8*)(BsM + (wn * 64 + j * 16 + fr) * 32 + fk);
#pragma unroll
        for (int i = 0; i < 4; ++i)
#pragma unroll
          for (int j = 0; j < 4; ++j)
            acc[i][j] = __builtin_amdgcn_mfma_f32_16x16x32_bf16(af[i], bfv[j], acc[i][j], 0, 0, 0);
        __syncthreads();
      }
#pragma unroll
      for (int j = 0; j < 4; ++j) {
        int col = wn * 64 + j * 16 + cidx;
        float bv = bb[col];
#pragma unroll
        for (int i = 0; i < 4; ++i) {
          int row = wm * 64 + i * 16 + rquad;
#pragma unroll
          for (int r = 0; r < 4; ++r) {
            float v = acc[i][j][r] + bv;
            if (layer == 0) v = fmaxf(v, 0.f);
            hw[row + r][col] = f2bf(v);
          }
        }
      }
      __syncthreads();
    }
    {
      int r = t >> 1, half = t & 1;
#pragma unroll
      for (int c8 = 0; c8 < 8; ++c8)
        *(bf16x8*)(a.ajoin + (size_t)(m0 + r) * 640 + 512 + half * 64 + c8 * 8) =
            *(const bf16x8*)(&hw[r][half * 64 + c8 * 8]);
    }
    return;
  }
  if (b >= 128) {            // ---- W_f fuse GEMM (depth-2 pipelined)
    int idx = b - 128;                 // 0..39
    int mt = idx & 7, nt = idx >> 3;   // M=1024 -> 8 mtiles, N=640 -> 5 ntiles
    gemm128_db(a.c_w1t, 512, nullptr, 0, 1024, a.wjbf, nullptr, a.wf_t, 640, 0, 512, mt, nt);
    return;
  }
  // ---- place with per-block self-scan
  __shared__ int pf[NCMD][4];
  __shared__ int tot[NCMD];
  int c = t >> 6, lane = t & 63;
  int v[8]; int s = 0;
#pragma unroll
  for (int q = 0; q < 8; ++q) { v[q] = a.wavecnt[c * 512 + lane * 8 + q]; s += v[q]; }
  int p = s;
#pragma unroll
  for (int m = 1; m < 64; m <<= 1) { int o = __shfl_up(p, m, 64); if (lane >= m) p += o; }
  int excl = p - s;
  if (lane == 63) tot[c] = p;
  if (lane == ((4 * b) >> 3)) {
    int base_off = (4 * b) & 7;
    int run = excl;
#pragma unroll
    for (int q = 0; q < 8; ++q) {
      if (q >= base_off && q < base_off + 4) pf[c][q - base_off] = run;
      run += v[q];
    }
  }
  __syncthreads();
  int soffs[NCMD + 1];
  soffs[0] = 0;
#pragma unroll
  for (int e = 0; e < NCMD; ++e) soffs[e + 1] = soffs[e] + tot[e];
  if (b == 0 && t == 0)
    for (int e = 0; e <= NCMD; ++e) a.offs[e] = soffs[e];
  int i = b * 256 + t;
  int mc = a.cmd[i];
  int lwid = t >> 6;
  int rank = 0, base = 0;
#pragma unroll
  for (int cv = 0; cv < NCMD; ++cv) {
    unsigned long long m = __ballot(mc == cv);
    if (mc == cv) {
      rank = __popcll(m & ((1ull << lane) - 1ull));
      base = soffs[cv] + pf[cv][lwid];
    }
  }
  a.perm[base + rank] = i;

  // ---- 128-row tile table for k_main ctrl path (block 0 only)
  if (b == 0) {
    int toff[NCMD + 1];
    toff[0] = 0;
#pragma unroll
    for (int ee = 0; ee < NCMD; ++ee) toff[ee + 1] = toff[ee] + ((tot[ee] + 127) >> 7);
    if (t == 0) a.ntl[0] = toff[NCMD];
    for (int ti = t; ti < toff[NCMD]; ti += 256) {
      int ee = 0;
      while (ti >= toff[ee + 1]) ++ee;
      a.tile_e[ti] = ee;
      a.tile_r0[ti] = soffs[ee] + (ti - toff[ee]) * 128;
    }
  }
}

// ---- k_main (R6-proven structure): z<2 -> ctrl1 (128-row tile table,
// perm-gathered, nt=z); z in {2,3} -> sp1 on NATURAL rows (nt=z-2).
struct MainArgs {
  const unsigned short* ajoin;
  const unsigned short* wf_t; const float* b_f;
  const unsigned short* sp_w1t; const float* sp_b1;
  unsigned short* ch1; unsigned short* sph1;
  const int* perm; const int* seg;
  const int* tile_e; const int* tile_r0; const int* ntl;
};
__launch_bounds__(256)
__global__ void k_main(MainArgs a) {
  const int z = blockIdx.z;
  if (z < 2) {
    int ti = blockIdx.x;
    if (ti >= a.ntl[0]) return;
    int e = a.tile_e[ti];
    int r0 = a.tile_r0[ti];
    int mc = a.seg[e + 1] - r0; if (mc > 128) mc = 128;
    gemm128_db(a.ajoin, 640, a.perm, r0, mc, a.wf_t + (size_t)e * 256 * 640,
               a.b_f + e * 256, a.ch1, 256, 1, 640, 0, z);
  } else {
    int mt = blockIdx.x;
    if (mt >= 256) return;
    gemm128_db(a.ajoin, 640, nullptr, 0, BB, a.sp_w1t, a.sp_b1,
               a.sph1, 256, 1, 512, mt, z - 2);
  }
}

// ------- k_vgemm: 64xN256 GEMM + exact final dot; depth-1 counted vmcnt ------
struct VArgs {
  const unsigned short* A_s; const unsigned short* A_c;
  const unsigned short* W_s; const unsigned short* W_c;
  const float* b_s; const float* b_c;
  const float* w3_s; const float* b3_s;
  const float* w3_c; const float* b3_c;
  const int* perm; const int* seg;
  float* out;
};
__launch_bounds__(256)
__global__ void k_vgemm(VArgs a) {
  __shared__ unsigned short As[2 * 64 * 32];    //  8 KB, 2 bufs
  __shared__ unsigned short Bs[2 * 256 * 32];   // 32 KB, 2 bufs
  const int z = blockIdx.z;
  const unsigned short* A; const unsigned short* W; const float* bi;
  int m_start, m_cnt;
  if (z == 4) { A = a.A_s; W = a.W_s; bi = a.b_s; m_start = 0; m_cnt = BB; }
  else {
    A = a.A_c; W = a.W_c + (size_t)z * 65536; bi = a.b_c + z * 256;
    m_start = a.seg[z]; m_cnt = a.seg[z + 1] - m_start;
  }
  const int m0 = blockIdx.x * 64;
  if (m0 >= m_cnt) return;
  const int t = threadIdx.x, w = t >> 6, lane = t & 63;
  const int fr = lane & 15, fk = RD_SLOT(lane);

  f32x4 acc[16];
#pragma unroll
  for (int j = 0; j < 16; ++j)
#pragma unroll
    for (int r = 0; r < 4; ++r) acc[j][r] = 0.f;

  int arow = m0 + w * 16 + (lane >> 2);
  if (arow >= m_cnt) arow = m_cnt - 1;
  const int sseg = SRC_SEG(lane);
  const unsigned short* ap = A + (size_t)(m_start + arow) * 256 + sseg;
  unsigned short* al = As + (w * 16) * 32;
  const unsigned short* bp[4]; unsigned short* bl[4];
#pragma unroll
  for (int it = 0; it < 4; ++it) {
    int brow = w * 64 + it * 16 + (lane >> 2);
    bp[it] = W + (size_t)brow * 256 + sseg;
    bl[it] = Bs + (w * 64 + it * 16) * 32;
  }

  // prologue: chunk 0 -> buf 0 (5 asyncs per lane)
  async16(ap, al);
#pragma unroll
  for (int it = 0; it < 4; ++it) async16(bp[it], bl[it]);

  for (int k = 0; k < 8; ++k) {
    const int cur = (k & 1) * 2048, curB = (k & 1) * 8192;
    if (k + 1 < 8) {
      const int nxt = ((k + 1) & 1) * 2048, nxtB = ((k + 1) & 1) * 8192;
      async16(ap + (k + 1) * 32, al + nxt);
#pragma unroll
      for (int it = 0; it < 4; ++it) async16(bp[it] + (k + 1) * 32, bl[it] + nxtB);
      asm volatile("s_waitcnt vmcnt(5)" ::: "memory");   // chunk k landed
    } else {
      asm volatile("s_waitcnt vmcnt(0)" ::: "memory");
    }
    asm volatile("s_barrier" ::: "memory");
    bf16x8 af = *(const bf16x8*)(As + cur + (w * 16 + fr) * 32 + fk);
    __builtin_amdgcn_s_setprio(1);
#pragma unroll
    for (int j = 0; j < 16; ++j) {
      bf16x8 bfv = *(const bf16x8*)(Bs + curB + (j * 16 + fr) * 32 + fk);
      acc[j] = __builtin_amdgcn_mfma_f32_16x16x32_bf16(af, bfv, acc[j], 0, 0, 0);
    }
    __builtin_amdgcn_s_setprio(0);
    asm volatile("s_barrier" ::: "memory");
  }

  const int rquad = (lane >> 4) * 4;
  float bcol[16];
#pragma unroll
  for (int j = 0; j < 16; ++j) bcol[j] = bi[j * 16 + fr];

  if (z == 4) {
    float aw[16];
#pragma unroll
    for (int j = 0; j < 16; ++j) aw[j] = a.w3_s[j * 16 + fr];
#pragma unroll
    for (int r = 0; r < 4; ++r) {
      float s = 0.f;
#pragma unroll
      for (int j = 0; j < 16; ++j)
        s = fmaf(fmaxf(acc[j][r] + bcol[j], 0.f), aw[j], s);
      s += __shfl_xor(s, 1, 64);
      s += __shfl_xor(s, 2, 64);
      s += __shfl_xor(s, 4, 64);
      s += __shfl_xor(s, 8, 64);
      int row = m0 + w * 16 + rquad + r;
      if (fr == 0 && row < m_cnt)
        a.out[row] = s + a.b3_s[0];                 // sph1 natural -> direct
    }
  } else {
    float aw0[16], aw1[16], aw2[16];
#pragma unroll
    for (int j = 0; j < 16; ++j) {
      const float* wp = a.w3_c + (size_t)z * 768 + (j * 16 + fr) * 3;
      aw0[j] = wp[0]; aw1[j] = wp[1]; aw2[j] = wp[2];
    }
#pragma unroll
    for (int r = 0; r < 4; ++r) {
      float s0 = 0.f, s1 = 0.f, s2 = 0.f;
#pragma unroll
      for (int j = 0; j < 16; ++j) {
        float v = fmaxf(acc[j][r] + bcol[j], 0.f);
        s0 = fmaf(v, aw0[j], s0);
        s1 = fmaf(v, aw1[j], s1);
        s2 = fmaf(v, aw2[j], s2);
      }
#pragma unroll
      for (int m = 1; m <= 8; m <<= 1) {
        s0 += __shfl_xor(s0, m, 64);
        s1 += __shfl_xor(s1, m, 64);
        s2 += __shfl_xor(s2, m, 64);
      }
      int row = m0 + w * 16 + rquad + r;
      if (fr == 0 && row < m_cnt) {
        int orig = a.perm[m_start + row];
        float a0 = s0 + a.b3_c[z * 3 + 0];
        float a1 = s1 + a.b3_c[z * 3 + 1];
        float a2 = s2 + a.b3_c[z * 3 + 2];
        a.out[BB + orig]     = 1.f / (1.f + __expf(-a0));   // throttle
        a.out[2 * BB + orig] = 1.f / (1.f + __expf(-a2));   // brake
        a.out[3 * BB + orig] = tanhf(a1);                   // steering
      }
    }
  }
}

static inline size_t align256(size_t x) { return (x + 255) & ~(size_t)255; }

extern "C" void kernel_launch(void* const* d_in, const int* in_sizes, int n_in,
                              void* d_out, int out_size, void* d_ws, size_t ws_size,
                              hipStream_t stream) {
  const float* feat   = (const float*)d_in[0];
  const float* speed  = (const float*)d_in[1];
  const int*   command= (const int*)d_in[2];
  const float* ms_w1  = (const float*)d_in[3];
  const float* ms_b1  = (const float*)d_in[4];
  const float* ms_w2  = (const float*)d_in[5];
  const float* ms_b2  = (const float*)d_in[6];
  const float* ms_w3  = (const float*)d_in[7];
  const float* ms_b3  = (const float*)d_in[8];
  const float* sp_w1  = (const float*)d_in[9];
  const float* sp_b1  = (const float*)d_in[10];
  const float* sp_w2  = (const float*)d_in[11];
  const float* sp_b2  = (const float*)d_in[12];
  const float* sp_w3  = (const float*)d_in[13];
  const float* sp_b3  = (const float*)d_in[14];
  const float* join_w = (const float*)d_in[15];
  const float* join_b = (const float*)d_in[16];
  const float* ctrl_w1= (const float*)d_in[17];
  const float* ctrl_b1= (const float*)d_in[18];
  const float* ctrl_w2= (const float*)d_in[19];
  const float* ctrl_b2= (const float*)d_in[20];
  const float* ctrl_w3= (const float*)d_in[21];
  const float* ctrl_b3= (const float*)d_in[22];
  float* out = (float*)d_out;

  char* ws = (char*)d_ws;
  size_t off = 0;
  auto alloc = [&](size_t bytes) -> char* { char* p = ws + off; off = align256(off + bytes); return p; };

  unsigned short* ajoin  = (unsigned short*)alloc((size_t)BB * 640 * 2);
  unsigned short* sph1   = (unsigned short*)alloc((size_t)BB * 256 * 2);
  unsigned short* ch1    = (unsigned short*)alloc((size_t)BB * 256 * 2);
  unsigned short* wtp    = (unsigned short*)alloc(1998848ull * 2);
  int* perm    = (int*)alloc((size_t)BB * 4);
  int* cnt     = (int*)alloc(64);        // offs[5] at cnt+4
  int* wavecnt = (int*)alloc(4 * 512 * 4);
  float* bf_part = (float*)alloc(4 * 8 * 256 * 4);
  float* b_f   = (float*)alloc(4 * 256 * 4);
  int* tile_e  = (int*)alloc(272 * 4);
  int* tile_r0 = (int*)alloc(272 * 4);
  int* ntl     = (int*)alloc(64);

  unsigned short* sp_w1t = wtp;                 // [256][512]
  unsigned short* sp_w2t = wtp + 131072;        // [256][256]
  unsigned short* ms_w2t = wtp + 196608;        // [128][128]
  unsigned short* ms_w3t = wtp + 212992;        // [128][128]
  unsigned short* c_w1t  = wtp + 229376;        // [4][256][512]
  unsigned short* c_w2t  = wtp + 753664;        // [4][256][256]
  unsigned short* wjbf   = wtp + 1015808;       // [640][512] straight bf16
  unsigned short* wf_t   = wtp + 1343488;       // [4][256][640] fused W_f^T

  PrepArgs P;
  P.s[0] = { sp_w1, sp_w1t, 512, 256, 512 };
  P.s[1] = { sp_w2, sp_w2t, 256, 256, 256 };
  P.s[2] = { ms_w2, ms_w2t, 128, 128, 128 };
  P.s[3] = { ms_w3, ms_w3t, 128, 128, 128 };
  for (int e = 0; e < 4; ++e) P.s[4 + e] = { ctrl_w1 + (size_t)e * 512 * 256, c_w1t + (size_t)e * 131072, 512, 256, 512 };
  for (int e = 0; e < 4; ++e) P.s[8 + e] = { ctrl_w2 + (size_t)e * 256 * 256, c_w2t + (size_t)e * 65536, 256, 256, 256 };
  P.start[0] = 0;
  for (int i = 0; i < 12; ++i)
    P.start[i + 1] = P.start[i] + (P.s[i].K >> 5) * (P.s[i].N >> 5);
  P.join_w = join_w; P.wjbf = wjbf;
  P.feat = feat; P.ajoin = ajoin;
  P.cmd = command; P.wavecnt = wavecnt;
  P.join_b = join_b; P.ctrl_w1 = ctrl_w1; P.bf_part = bf_part;
  int prep_blocks = 16384 + 320 + P.start[12] + 128 + 32;

  k_prep<<<prep_blocks, 256, 0, stream>>>(P);

  MidArgs Mi;
  Mi.cmd = command; Mi.wavecnt = wavecnt; Mi.perm = perm; Mi.offs = cnt + 4;
  Mi.c_w1t = c_w1t; Mi.wjbf = wjbf; Mi.wf_t = wf_t;
  Mi.speed = speed;
  Mi.ms_w1 = ms_w1; Mi.ms_b1 = ms_b1;
  Mi.ms_w2t = ms_w2t; Mi.ms_b2 = ms_b2;
  Mi.ms_w3t = ms_w3t; Mi.ms_b3 = ms_b3;
  Mi.ajoin = ajoin;
  Mi.bf_part = bf_part; Mi.ctrl_b1 = ctrl_b1; Mi.b_f = b_f;
  Mi.tile_e = tile_e; Mi.tile_r0 = tile_r0; Mi.ntl = ntl;
  // dyn LDS = max(ms module 43008, gemm128_db 49152)
  k_mid<<<428, 256, 49152, stream>>>(Mi);

  MainArgs Ma;
  Ma.ajoin = ajoin; Ma.wf_t = wf_t; Ma.b_f = b_f;
  Ma.sp_w1t = sp_w1t; Ma.sp_b1 = sp_b1;
  Ma.ch1 = ch1; Ma.sph1 = sph1;
  Ma.perm = perm; Ma.seg = cnt + 4;
  Ma.tile_e = tile_e; Ma.tile_r0 = tile_r0; Ma.ntl = ntl;
  // x: ctrl tiles <= 259 (z<2), sp mtiles = 256 (z in {2,3}); 48 KB dyn LDS
  k_main<<<dim3(260, 1, 4), 256, 49152, stream>>>(Ma);

  VArgs V;
  V.A_s = sph1; V.A_c = ch1; V.W_s = sp_w2t; V.W_c = c_w2t;
  V.b_s = sp_b2; V.b_c = ctrl_b2;
  V.w3_s = sp_w3; V.b3_s = sp_b3; V.w3_c = ctrl_w3; V.b3_c = ctrl_b3;
  V.perm = perm; V.seg = cnt + 4; V.out = out;
  k_vgemm<<<dim3(512, 1, 5), 256, 0, stream>>>(V);
}